// Round 10
// baseline (229.357 us; speedup 1.0000x reference)
//
#include <hip/hip_runtime.h>
#include <hip/hip_bf16.h>

#define NQ 4096
#define NK 8192
#define NSPLIT 8
#define KSPAN (NK / NSPLIT)
#define BK 64
#define PST 72

// 0.125 (1/sqrt(64)) * log2(e): scores in log2 domain; no max subtraction needed
// (|S| <= ~14 in log2 domain, exp2 can't overflow; scale cancels in O/l)
#define QSCALE 0.1803368801111204f

typedef short v8s __attribute__((ext_vector_type(8)));
typedef float v4f __attribute__((ext_vector_type(4)));

static __device__ __forceinline__ unsigned short f2bf(float f) {
    unsigned int u = __float_as_uint(f);
    u = (u + 0x7FFFu + ((u >> 16) & 1u)) >> 16;
    return (unsigned short)u;
}
static __device__ __forceinline__ float bf2f(unsigned short h) {
    return __uint_as_float(((unsigned int)h) << 16);
}
static __device__ __forceinline__ unsigned int pkbf(float a, float b) {
    union { __hip_bfloat162 h; unsigned int u; } cv;
    cv.h = __float22bfloat162_rn(make_float2(a, b));
    return cv.u;
}
static __device__ __forceinline__ void split8(const float* a, v8s& hi, v8s& lo) {
#pragma unroll
    for (int j = 0; j < 8; ++j) {
        unsigned short h = f2bf(a[j]);
        hi[j] = (short)h;
        lo[j] = (short)f2bf(a[j] - bf2f(h));
    }
}
// gather a W^T[col][k0..k0+7] B-fragment from fp32 W[k][col] (ld=256), hi/lo planes
static __device__ __forceinline__ void wgather(const float* __restrict__ W,
                                               int k0, int col, v8s& wh, v8s& wl) {
    float wv[8];
#pragma unroll
    for (int j = 0; j < 8; ++j) wv[j] = W[(size_t)(k0 + j) * 256 + col];
    split8(wv, wh, wl);
}

// ---- fused QKV projection, inline W split
// grid 1280: b<256 Q (16 rows), b<768 K (16 rows), else V (16 rows). wave = 64 cols.
__global__ __launch_bounds__(256) void qkv_kernel(
    const float* __restrict__ query, const float* __restrict__ key,
    const float* __restrict__ value,
    const float* __restrict__ Wq, const float* __restrict__ Wk,
    const float* __restrict__ Wv,
    const float* __restrict__ bq, const float* __restrict__ bk,
    const float* __restrict__ bv,
    unsigned short* __restrict__ Qb, unsigned short* __restrict__ Kb,
    unsigned short* __restrict__ Vt, const int* __restrict__ nexp)
{
    const int b = blockIdx.x;
    const int t = threadIdx.x, w = t >> 6, lane = t & 63;
    const int quad = lane >> 4, l16 = lane & 15;
    const int colbase = w * 64;

    if (b < 256) {
        // ---- Q: KD=256
        const int n0 = b * 16;
        v4f acc[4];
#pragma unroll
        for (int ct = 0; ct < 4; ++ct) {
            const float bb = bq[colbase + ct * 16 + l16];
            acc[ct] = v4f{bb, bb, bb, bb};
        }
        const float* arow = query + (size_t)(n0 + l16) * 256 + quad * 8;
#pragma unroll
        for (int k0 = 0; k0 < 256; k0 += 32) {
            float av[8];
            *(float4*)av = *(const float4*)(arow + k0);
            *(float4*)(av + 4) = *(const float4*)(arow + k0 + 4);
            v8s ah, al;
            split8(av, ah, al);
#pragma unroll
            for (int ct = 0; ct < 4; ++ct) {
                v8s wh, wl;
                wgather(Wq, k0 + quad * 8, colbase + ct * 16 + l16, wh, wl);
                acc[ct] = __builtin_amdgcn_mfma_f32_16x16x32_bf16(al, wh, acc[ct], 0, 0, 0);
                acc[ct] = __builtin_amdgcn_mfma_f32_16x16x32_bf16(ah, wl, acc[ct], 0, 0, 0);
                acc[ct] = __builtin_amdgcn_mfma_f32_16x16x32_bf16(ah, wh, acc[ct], 0, 0, 0);
            }
        }
#pragma unroll
        for (int ct = 0; ct < 4; ++ct) {
            const int d = ct * 16 + l16;
            const int j = d >> 1;
            const float freq = exp2f(-(float)(j & 15) * 1.66096404744368f);
            const bool isx = (j < 16), odd = (d & 1);
#pragma unroll
            for (int r = 0; r < 4; ++r) {
                const int p = n0 + quad * 4 + r;
                const float tpos = isx ? (float)(p & 63) : (float)(p >> 6);
                float sn, cs;
                __sincosf(tpos * freq, &sn, &cs);
                const float x = acc[ct][r];
                const float xp = __shfl_xor(x, 1, 64);
                const float y = odd ? fmaf(x, cs, xp * sn) : fmaf(x, cs, -xp * sn);
                Qb[((size_t)(w * NQ + p) << 6) + d] = f2bf(y * QSCALE);
            }
        }
    } else {
        const bool isK = (b < 768);
        const int n0 = (isK ? (b - 256) : (b - 768)) * 16;
        const float* X = isK ? key : value;
        const float* W = isK ? Wk : Wv;
        const float* bias = isK ? bk : bv;
        v4f acc[4];
#pragma unroll
        for (int ct = 0; ct < 4; ++ct) {
            const float bb = bias[colbase + ct * 16 + l16];
            acc[ct] = v4f{bb, bb, bb, bb};
        }
        const float* arow = X + (size_t)(n0 + l16) * 64 + quad * 8;
#pragma unroll
        for (int k0 = 0; k0 < 64; k0 += 32) {
            float av[8];
            *(float4*)av = *(const float4*)(arow + k0);
            *(float4*)(av + 4) = *(const float4*)(arow + k0 + 4);
            v8s ah, al;
            split8(av, ah, al);
#pragma unroll
            for (int ct = 0; ct < 4; ++ct) {
                v8s wh, wl;
                wgather(W, k0 + quad * 8, colbase + ct * 16 + l16, wh, wl);
                acc[ct] = __builtin_amdgcn_mfma_f32_16x16x32_bf16(al, wh, acc[ct], 0, 0, 0);
                acc[ct] = __builtin_amdgcn_mfma_f32_16x16x32_bf16(ah, wl, acc[ct], 0, 0, 0);
                acc[ct] = __builtin_amdgcn_mfma_f32_16x16x32_bf16(ah, wh, acc[ct], 0, 0, 0);
            }
        }
        if (isK) {
            const int nro = NK - *nexp;
#pragma unroll
            for (int ct = 0; ct < 4; ++ct) {
                const int d = ct * 16 + l16;
                const int j = d >> 1;
                const float freq = exp2f(-(float)(j & 15) * 1.66096404744368f);
                const bool isx = (j < 16), odd = (d & 1);
#pragma unroll
                for (int r = 0; r < 4; ++r) {
                    const int p = n0 + quad * 4 + r;
                    const int pc = p & 4095;
                    const float tpos = isx ? (float)(pc & 63) : (float)(pc >> 6);
                    float sn, cs;
                    __sincosf(tpos * freq, &sn, &cs);
                    const float x = acc[ct][r];
                    const float xp = __shfl_xor(x, 1, 64);
                    float y = odd ? fmaf(x, cs, xp * sn) : fmaf(x, cs, -xp * sn);
                    y = (p < nro) ? y : x;
                    Kb[((size_t)(w * NK + p) << 6) + d] = f2bf(y);
                }
            }
        } else {
#pragma unroll
            for (int ct = 0; ct < 4; ++ct) {
                const int col = colbase + ct * 16 + l16;
                uint2 u = make_uint2(pkbf(acc[ct][0], acc[ct][1]),
                                     pkbf(acc[ct][2], acc[ct][3]));
                *(uint2*)(Vt + (size_t)col * NK + n0 + quad * 4) = u;
            }
        }
    }
}

// ---- flash attention: 1024 blocks = qt(32) x h(4) x s(8); 4 waves x 32 q-rows
// K/V fragments DIRECT from global (L1-shared across the block's 4 waves,
// L2 XCD-pinned via s=blk&7). LDS only for the per-wave P round-trip.
// NO barriers, NO DMA. no-max softmax.
__global__ __launch_bounds__(256) void attn_kernel(
    const unsigned short* __restrict__ Qb, const unsigned short* __restrict__ Kb,
    const unsigned short* __restrict__ Vt, unsigned short* __restrict__ Opart,
    float* __restrict__ Lbuf)
{
    __shared__ alignas(16) unsigned short Pl[4 * 32 * PST];

    const int blk = blockIdx.x;
    const int s = blk & 7, h = (blk >> 3) & 3, qt = blk >> 5;
    const int t = threadIdx.x;
    const int w = t >> 6, lane = t & 63;
    const int quad = lane >> 4, l16 = lane & 15;

    const int q0 = qt * 128 + w * 32;
    v8s qf[2][2];
#pragma unroll
    for (int g = 0; g < 2; ++g) {
        const unsigned short* qr = Qb + ((size_t)(h * NQ + q0 + g * 16 + l16) << 6) + quad * 8;
        qf[g][0] = *(const v8s*)qr;
        qf[g][1] = *(const v8s*)(qr + 32);
    }

    v4f O[4][2];
#pragma unroll
    for (int dt = 0; dt < 4; ++dt)
#pragma unroll
        for (int g = 0; g < 2; ++g) O[dt][g] = v4f{0.f, 0.f, 0.f, 0.f};
    float psum[2] = {0.f, 0.f};

    const unsigned short* Kbase = Kb + (((size_t)h * NK + s * KSPAN) << 6);
    const unsigned short* Vbase = Vt + (size_t)(h * 64) * NK + s * KSPAN;
    unsigned short* Pw = &Pl[w * 32 * PST];

    for (int k0 = 0; k0 < KSPAN; k0 += BK) {
        // K fragments: lane-fixed rows, b128 each (issued early, L1-shared)
        v8s kf[4][2];
#pragma unroll
        for (int tt = 0; tt < 4; ++tt) {
            const unsigned short* kr = Kbase + ((size_t)(k0 + tt * 16 + l16) << 6) + quad * 8;
            kf[tt][0] = *(const v8s*)kr;
            kf[tt][1] = *(const v8s*)(kr + 32);
        }
        // V fragments: issued now, consumed after softmax (~1000 cyc of hiding)
        v8s vf[4][2];
#pragma unroll
        for (int dt = 0; dt < 4; ++dt) {
            const unsigned short* vr = Vbase + (size_t)(dt * 16 + l16) * NK + k0 + quad * 8;
            vf[dt][0] = *(const v8s*)vr;
            vf[dt][1] = *(const v8s*)(vr + 32);
        }

        // S^T = K Q^T ; exp2 immediately (no max); stash P[q][k] per-wave
#pragma unroll
        for (int tt = 0; tt < 4; ++tt) {
#pragma unroll
            for (int g = 0; g < 2; ++g) {
                v4f a = v4f{0.f, 0.f, 0.f, 0.f};
                a = __builtin_amdgcn_mfma_f32_16x16x32_bf16(kf[tt][0], qf[g][0], a, 0, 0, 0);
                a = __builtin_amdgcn_mfma_f32_16x16x32_bf16(kf[tt][1], qf[g][1], a, 0, 0, 0);
                const float e0 = __builtin_amdgcn_exp2f(a[0]);
                const float e1 = __builtin_amdgcn_exp2f(a[1]);
                const float e2 = __builtin_amdgcn_exp2f(a[2]);
                const float e3 = __builtin_amdgcn_exp2f(a[3]);
                psum[g] += (e0 + e1) + (e2 + e3);
                *(uint2*)(&Pw[(g * 16 + l16) * PST + tt * 16 + quad * 4]) =
                    make_uint2(pkbf(e0, e1), pkbf(e2, e3));
            }
        }
        __asm__ volatile("s_waitcnt lgkmcnt(0)" ::: "memory");

        v8s pf[2][2];
#pragma unroll
        for (int g = 0; g < 2; ++g) {
            const unsigned short* pr = &Pw[(g * 16 + l16) * PST + quad * 8];
            pf[g][0] = *(const v8s*)pr;
            pf[g][1] = *(const v8s*)(pr + 32);
        }
#pragma unroll
        for (int dt = 0; dt < 4; ++dt) {
#pragma unroll
            for (int g = 0; g < 2; ++g) {
                v4f a = O[dt][g];
                a = __builtin_amdgcn_mfma_f32_16x16x32_bf16(vf[dt][0], pf[g][0], a, 0, 0, 0);
                a = __builtin_amdgcn_mfma_f32_16x16x32_bf16(vf[dt][1], pf[g][1], a, 0, 0, 0);
                O[dt][g] = a;
            }
        }
    }

#pragma unroll
    for (int g = 0; g < 2; ++g) {
        float p = psum[g];
        p += __shfl_xor(p, 16, 64);
        p += __shfl_xor(p, 32, 64);
        psum[g] = p;
    }
    unsigned short* Ob = Opart + (size_t)blk * 8192;
#pragma unroll
    for (int g = 0; g < 2; ++g) {
        const int row = w * 32 + g * 16 + l16;
#pragma unroll
        for (int dt = 0; dt < 4; ++dt) {
            uint2 u = make_uint2(pkbf(O[dt][g][0], O[dt][g][1]),
                                 pkbf(O[dt][g][2], O[dt][g][3]));
            *(uint2*)(Ob + row * 64 + dt * 16 + quad * 4) = u;
        }
        if (quad == 0) Lbuf[blk * 128 + row] = psum[g];
    }
}

// ---- output projection: split-sum in VALU first, then 1x MFMA; fused 1/l
__global__ __launch_bounds__(256) void oproj_kernel(
    const unsigned short* __restrict__ Opart, const float* __restrict__ Lbuf,
    const float* __restrict__ Wo, const float* __restrict__ bo,
    float* __restrict__ out)
{
    const int t = threadIdx.x, w = t >> 6, lane = t & 63;
    const int quad = lane >> 4, l16 = lane & 15;
    const int n0 = blockIdx.x * 16, colbase = w * 64;
    const int qt32 = (n0 >> 7) * 32;
    const int rbase = n0 & 127;

    float linv[4];
#pragma unroll
    for (int hh = 0; hh < 4; ++hh) {
        float ls = 0.f;
#pragma unroll
        for (int sp = 0; sp < NSPLIT; ++sp)
            ls += Lbuf[(qt32 + hh * 8 + sp) * 128 + rbase + l16];
        linv[hh] = 1.f / ls;
    }
    v4f acc[4];
#pragma unroll
    for (int ct = 0; ct < 4; ++ct) {
        const float bb = bo[colbase + ct * 16 + l16];
        acc[ct] = v4f{bb, bb, bb, bb};
    }
#pragma unroll
    for (int k0 = 0; k0 < 256; k0 += 32) {
        const int hh = k0 >> 6;
        const int d0 = (k0 & 63) + quad * 8;
        float av[8] = {0.f, 0.f, 0.f, 0.f, 0.f, 0.f, 0.f, 0.f};
#pragma unroll
        for (int sp = 0; sp < NSPLIT; ++sp) {
            const v8s A = *(const v8s*)(Opart + (size_t)(qt32 + hh * 8 + sp) * 8192
                                        + (rbase + l16) * 64 + d0);
#pragma unroll
            for (int j = 0; j < 8; ++j) av[j] += bf2f((unsigned short)A[j]);
        }
#pragma unroll
        for (int j = 0; j < 8; ++j) av[j] *= linv[hh];
        v8s ah, al;
        split8(av, ah, al);
#pragma unroll
        for (int ct = 0; ct < 4; ++ct) {
            v8s wh, wl;
            wgather(Wo, k0 + quad * 8, colbase + ct * 16 + l16, wh, wl);
            acc[ct] = __builtin_amdgcn_mfma_f32_16x16x32_bf16(al, wh, acc[ct], 0, 0, 0);
            acc[ct] = __builtin_amdgcn_mfma_f32_16x16x32_bf16(ah, wl, acc[ct], 0, 0, 0);
            acc[ct] = __builtin_amdgcn_mfma_f32_16x16x32_bf16(ah, wh, acc[ct], 0, 0, 0);
        }
    }
#pragma unroll
    for (int ct = 0; ct < 4; ++ct)
#pragma unroll
        for (int r = 0; r < 4; ++r)
            out[(size_t)(n0 + quad * 4 + r) * 256 + colbase + ct * 16 + l16] = acc[ct][r];
}

extern "C" void kernel_launch(void* const* d_in, const int* in_sizes, int n_in,
                              void* d_out, int out_size, void* d_ws, size_t ws_size,
                              hipStream_t stream) {
    const float* query = (const float*)d_in[0];
    const float* key   = (const float*)d_in[1];
    const float* value = (const float*)d_in[2];
    const float* Wq    = (const float*)d_in[3];
    const float* bq    = (const float*)d_in[4];
    const float* Wk    = (const float*)d_in[5];
    const float* bk    = (const float*)d_in[6];
    const float* Wv    = (const float*)d_in[7];
    const float* bv    = (const float*)d_in[8];
    const float* Wo    = (const float*)d_in[9];
    const float* bo    = (const float*)d_in[10];
    const int*   nex   = (const int*)d_in[11];

    char* ws = (char*)d_ws;
    unsigned short* Qb    = (unsigned short*)(ws);                              // 2 MB
    unsigned short* Kb    = (unsigned short*)(ws + (size_t)2 * 1024 * 1024);    // 4 MB
    unsigned short* Vt    = (unsigned short*)(ws + (size_t)6 * 1024 * 1024);    // 4 MB
    unsigned short* Opart = (unsigned short*)(ws + (size_t)10 * 1024 * 1024);   // 16 MB bf16
    float* Lbuf           = (float*)(ws + (size_t)26 * 1024 * 1024);            // 512 KB
    float* out            = (float*)d_out;

    qkv_kernel<<<1280, 256, 0, stream>>>(query, key, value, Wq, Wk, Wv,
                                         bq, bk, bv, Qb, Kb, Vt, nex);
    attn_kernel<<<1024, 256, 0, stream>>>(Qb, Kb, Vt, Opart, Lbuf);
    oproj_kernel<<<256, 256, 0, stream>>>(Opart, Lbuf, Wo, bo, out);
}

// Round 11
// 163.528 us; speedup vs baseline: 1.4026x; 1.4026x over previous
//
#include <hip/hip_runtime.h>
#include <hip/hip_bf16.h>

#define NQ 4096
#define NK 8192
#define NSPLIT 8
#define KSPAN (NK / NSPLIT)
#define BK 64
#define PST 72

// 0.125 (1/sqrt(64)) * log2(e): scores in log2 domain; no max subtraction needed
// (|S| <= ~14 in log2 domain, exp2 can't overflow; scale cancels in O/l)
#define QSCALE 0.1803368801111204f

typedef short v8s __attribute__((ext_vector_type(8)));
typedef float v4f __attribute__((ext_vector_type(4)));

static __device__ __forceinline__ unsigned short f2bf(float f) {
    unsigned int u = __float_as_uint(f);
    u = (u + 0x7FFFu + ((u >> 16) & 1u)) >> 16;
    return (unsigned short)u;
}
static __device__ __forceinline__ float bf2f(unsigned short h) {
    return __uint_as_float(((unsigned int)h) << 16);
}
static __device__ __forceinline__ unsigned int pkbf(float a, float b) {
    union { __hip_bfloat162 h; unsigned int u; } cv;
    cv.h = __float22bfloat162_rn(make_float2(a, b));
    return cv.u;
}
static __device__ __forceinline__ void split8(const float* a, v8s& hi, v8s& lo) {
#pragma unroll
    for (int j = 0; j < 8; ++j) {
        unsigned short h = f2bf(a[j]);
        hi[j] = (short)h;
        lo[j] = (short)f2bf(a[j] - bf2f(h));
    }
}
// gather a W^T[col][k0..k0+7] B-fragment from fp32 W[k][col] (ld=256), hi/lo planes
static __device__ __forceinline__ void wgather(const float* __restrict__ W,
                                               int k0, int col, v8s& wh, v8s& wl) {
    float wv[8];
#pragma unroll
    for (int j = 0; j < 8; ++j) wv[j] = W[(size_t)(k0 + j) * 256 + col];
    split8(wv, wh, wl);
}
// async global->LDS, 16B/lane; dest = uniform base + lane*16
static __device__ __forceinline__ void dma16(const unsigned short* g, unsigned short* l) {
    __builtin_amdgcn_global_load_lds(
        (const __attribute__((address_space(1))) unsigned int*)(const void*)g,
        (__attribute__((address_space(3))) unsigned int*)(void*)l, 16, 0, 0);
}

// ---- fused QKV projection, inline W split (R9, proven)
// grid 1280: b<256 Q (16 rows), b<768 K (16 rows), else V (16 rows). wave = 64 cols.
__global__ __launch_bounds__(256) void qkv_kernel(
    const float* __restrict__ query, const float* __restrict__ key,
    const float* __restrict__ value,
    const float* __restrict__ Wq, const float* __restrict__ Wk,
    const float* __restrict__ Wv,
    const float* __restrict__ bq, const float* __restrict__ bk,
    const float* __restrict__ bv,
    unsigned short* __restrict__ Qb, unsigned short* __restrict__ Kb,
    unsigned short* __restrict__ Vt, const int* __restrict__ nexp)
{
    const int b = blockIdx.x;
    const int t = threadIdx.x, w = t >> 6, lane = t & 63;
    const int quad = lane >> 4, l16 = lane & 15;
    const int colbase = w * 64;

    if (b < 256) {
        // ---- Q: KD=256
        const int n0 = b * 16;
        v4f acc[4];
#pragma unroll
        for (int ct = 0; ct < 4; ++ct) {
            const float bb = bq[colbase + ct * 16 + l16];
            acc[ct] = v4f{bb, bb, bb, bb};
        }
        const float* arow = query + (size_t)(n0 + l16) * 256 + quad * 8;
#pragma unroll
        for (int k0 = 0; k0 < 256; k0 += 32) {
            float av[8];
            *(float4*)av = *(const float4*)(arow + k0);
            *(float4*)(av + 4) = *(const float4*)(arow + k0 + 4);
            v8s ah, al;
            split8(av, ah, al);
#pragma unroll
            for (int ct = 0; ct < 4; ++ct) {
                v8s wh, wl;
                wgather(Wq, k0 + quad * 8, colbase + ct * 16 + l16, wh, wl);
                acc[ct] = __builtin_amdgcn_mfma_f32_16x16x32_bf16(al, wh, acc[ct], 0, 0, 0);
                acc[ct] = __builtin_amdgcn_mfma_f32_16x16x32_bf16(ah, wl, acc[ct], 0, 0, 0);
                acc[ct] = __builtin_amdgcn_mfma_f32_16x16x32_bf16(ah, wh, acc[ct], 0, 0, 0);
            }
        }
#pragma unroll
        for (int ct = 0; ct < 4; ++ct) {
            const int d = ct * 16 + l16;
            const int j = d >> 1;
            const float freq = exp2f(-(float)(j & 15) * 1.66096404744368f);
            const bool isx = (j < 16), odd = (d & 1);
#pragma unroll
            for (int r = 0; r < 4; ++r) {
                const int p = n0 + quad * 4 + r;
                const float tpos = isx ? (float)(p & 63) : (float)(p >> 6);
                float sn, cs;
                __sincosf(tpos * freq, &sn, &cs);
                const float x = acc[ct][r];
                const float xp = __shfl_xor(x, 1, 64);
                const float y = odd ? fmaf(x, cs, xp * sn) : fmaf(x, cs, -xp * sn);
                Qb[((size_t)(w * NQ + p) << 6) + d] = f2bf(y * QSCALE);
            }
        }
    } else {
        const bool isK = (b < 768);
        const int n0 = (isK ? (b - 256) : (b - 768)) * 16;
        const float* X = isK ? key : value;
        const float* W = isK ? Wk : Wv;
        const float* bias = isK ? bk : bv;
        v4f acc[4];
#pragma unroll
        for (int ct = 0; ct < 4; ++ct) {
            const float bb = bias[colbase + ct * 16 + l16];
            acc[ct] = v4f{bb, bb, bb, bb};
        }
        const float* arow = X + (size_t)(n0 + l16) * 64 + quad * 8;
#pragma unroll
        for (int k0 = 0; k0 < 64; k0 += 32) {
            float av[8];
            *(float4*)av = *(const float4*)(arow + k0);
            *(float4*)(av + 4) = *(const float4*)(arow + k0 + 4);
            v8s ah, al;
            split8(av, ah, al);
#pragma unroll
            for (int ct = 0; ct < 4; ++ct) {
                v8s wh, wl;
                wgather(W, k0 + quad * 8, colbase + ct * 16 + l16, wh, wl);
                acc[ct] = __builtin_amdgcn_mfma_f32_16x16x32_bf16(al, wh, acc[ct], 0, 0, 0);
                acc[ct] = __builtin_amdgcn_mfma_f32_16x16x32_bf16(ah, wl, acc[ct], 0, 0, 0);
                acc[ct] = __builtin_amdgcn_mfma_f32_16x16x32_bf16(ah, wh, acc[ct], 0, 0, 0);
            }
        }
        if (isK) {
            const int nro = NK - *nexp;
#pragma unroll
            for (int ct = 0; ct < 4; ++ct) {
                const int d = ct * 16 + l16;
                const int j = d >> 1;
                const float freq = exp2f(-(float)(j & 15) * 1.66096404744368f);
                const bool isx = (j < 16), odd = (d & 1);
#pragma unroll
                for (int r = 0; r < 4; ++r) {
                    const int p = n0 + quad * 4 + r;
                    const int pc = p & 4095;
                    const float tpos = isx ? (float)(pc & 63) : (float)(pc >> 6);
                    float sn, cs;
                    __sincosf(tpos * freq, &sn, &cs);
                    const float x = acc[ct][r];
                    const float xp = __shfl_xor(x, 1, 64);
                    float y = odd ? fmaf(x, cs, xp * sn) : fmaf(x, cs, -xp * sn);
                    y = (p < nro) ? y : x;
                    Kb[((size_t)(w * NK + p) << 6) + d] = f2bf(y);
                }
            }
        } else {
#pragma unroll
            for (int ct = 0; ct < 4; ++ct) {
                const int col = colbase + ct * 16 + l16;
                uint2 u = make_uint2(pkbf(acc[ct][0], acc[ct][1]),
                                     pkbf(acc[ct][2], acc[ct][3]));
                *(uint2*)(Vt + (size_t)col * NK + n0 + quad * 4) = u;
            }
        }
    }
}

// ---- flash attention: 1024 blocks = qt(32) x h(4) x s(8); 4 waves x 32 q-rows
// DOUBLE-BUFFERED DMA staging: one barrier/iter, DMA(i+1) overlaps compute(i).
// XOR chunk swizzle, no-max softmax, per-wave P round-trip.
__global__ __launch_bounds__(256) void attn_kernel(
    const unsigned short* __restrict__ Qb, const unsigned short* __restrict__ Kb,
    const unsigned short* __restrict__ Vt, unsigned short* __restrict__ Opart,
    float* __restrict__ Lbuf)
{
    __shared__ alignas(16) unsigned short Kl[2][64 * 64];
    __shared__ alignas(16) unsigned short Vl[2][64 * 64];
    __shared__ alignas(16) unsigned short Pl[4 * 32 * PST];

    const int blk = blockIdx.x;
    const int s = blk & 7, h = (blk >> 3) & 3, qt = blk >> 5;
    const int t = threadIdx.x;
    const int w = t >> 6, lane = t & 63;
    const int quad = lane >> 4, l16 = lane & 15;

    const int q0 = qt * 128 + w * 32;
    v8s qf[2][2];
#pragma unroll
    for (int g = 0; g < 2; ++g) {
        const unsigned short* qr = Qb + ((size_t)(h * NQ + q0 + g * 16 + l16) << 6) + quad * 8;
        qf[g][0] = *(const v8s*)qr;
        qf[g][1] = *(const v8s*)(qr + 32);
    }

    v4f O[4][2];
#pragma unroll
    for (int dt = 0; dt < 4; ++dt)
#pragma unroll
        for (int g = 0; g < 2; ++g) O[dt][g] = v4f{0.f, 0.f, 0.f, 0.f};
    float psum[2] = {0.f, 0.f};

    const unsigned short* Kbase = Kb + (((size_t)h * NK + s * KSPAN) << 6);
    const unsigned short* Vbase = Vt + (size_t)(h * 64) * NK + s * KSPAN;

    const int srow = lane >> 3;            // 0..7
    const int schunk = (lane & 7) ^ srow;  // swizzled 16B chunk
    const int c0off = ((quad ^ (l16 & 7)) * 8);
    const int c1off = c0off ^ 32;
    unsigned short* Pw = &Pl[w * 32 * PST];

    // prologue: DMA tile 0 into buffer 0
#pragma unroll
    for (int half = 0; half < 2; ++half) {
        const int r0 = w * 16 + half * 8;
        dma16(Kbase + ((size_t)(r0 + srow) << 6) + schunk * 8, &Kl[0][r0 * 64]);
        dma16(Vbase + (size_t)(r0 + srow) * NK + schunk * 8, &Vl[0][r0 * 64]);
    }

    for (int k0 = 0; k0 < KSPAN; k0 += BK) {
        const int cur = (k0 >> 6) & 1, nxt = cur ^ 1;
        // barrier: (a) everyone finished reading buf[nxt] (last overwritten 2 iters
        // ago, consumed last iter); (b) vmcnt drain completes DMA into buf[cur],
        // which has had a full tile-compute to fly.
        __syncthreads();
        if (k0 + BK < KSPAN) {
            const int kn = k0 + BK;
#pragma unroll
            for (int half = 0; half < 2; ++half) {
                const int r0 = w * 16 + half * 8;
                dma16(Kbase + ((size_t)(kn + r0 + srow) << 6) + schunk * 8, &Kl[nxt][r0 * 64]);
                dma16(Vbase + (size_t)(r0 + srow) * NK + kn + schunk * 8, &Vl[nxt][r0 * 64]);
            }
        }

        // S^T = K Q^T ; exp2 immediately (no max); stash P[q][k] per-wave
#pragma unroll
        for (int tt = 0; tt < 4; ++tt) {
            const unsigned short* kr = &Kl[cur][(tt * 16 + l16) * 64];
            const v8s kf0 = *(const v8s*)(kr + c0off);
            const v8s kf1 = *(const v8s*)(kr + c1off);
#pragma unroll
            for (int g = 0; g < 2; ++g) {
                v4f a = v4f{0.f, 0.f, 0.f, 0.f};
                a = __builtin_amdgcn_mfma_f32_16x16x32_bf16(kf0, qf[g][0], a, 0, 0, 0);
                a = __builtin_amdgcn_mfma_f32_16x16x32_bf16(kf1, qf[g][1], a, 0, 0, 0);
                const float e0 = __builtin_amdgcn_exp2f(a[0]);
                const float e1 = __builtin_amdgcn_exp2f(a[1]);
                const float e2 = __builtin_amdgcn_exp2f(a[2]);
                const float e3 = __builtin_amdgcn_exp2f(a[3]);
                psum[g] += (e0 + e1) + (e2 + e3);
                *(uint2*)(&Pw[(g * 16 + l16) * PST + tt * 16 + quad * 4]) =
                    make_uint2(pkbf(e0, e1), pkbf(e2, e3));
            }
        }
        __asm__ volatile("s_waitcnt lgkmcnt(0)" ::: "memory");

        v8s pf[2][2];
#pragma unroll
        for (int g = 0; g < 2; ++g) {
            const unsigned short* pr = &Pw[(g * 16 + l16) * PST + quad * 8];
            pf[g][0] = *(const v8s*)pr;
            pf[g][1] = *(const v8s*)(pr + 32);
        }
#pragma unroll
        for (int dt = 0; dt < 4; ++dt) {
            const unsigned short* vr = &Vl[cur][(dt * 16 + l16) * 64];
            const v8s vf0 = *(const v8s*)(vr + c0off);
            const v8s vf1 = *(const v8s*)(vr + c1off);
#pragma unroll
            for (int g = 0; g < 2; ++g) {
                v4f a = O[dt][g];
                a = __builtin_amdgcn_mfma_f32_16x16x32_bf16(vf0, pf[g][0], a, 0, 0, 0);
                a = __builtin_amdgcn_mfma_f32_16x16x32_bf16(vf1, pf[g][1], a, 0, 0, 0);
                O[dt][g] = a;
            }
        }
    }

#pragma unroll
    for (int g = 0; g < 2; ++g) {
        float p = psum[g];
        p += __shfl_xor(p, 16, 64);
        p += __shfl_xor(p, 32, 64);
        psum[g] = p;
    }
    unsigned short* Ob = Opart + (size_t)blk * 8192;
#pragma unroll
    for (int g = 0; g < 2; ++g) {
        const int row = w * 32 + g * 16 + l16;
#pragma unroll
        for (int dt = 0; dt < 4; ++dt) {
            uint2 u = make_uint2(pkbf(O[dt][g][0], O[dt][g][1]),
                                 pkbf(O[dt][g][2], O[dt][g][3]));
            *(uint2*)(Ob + row * 64 + dt * 16 + quad * 4) = u;
        }
        if (quad == 0) Lbuf[blk * 128 + row] = psum[g];
    }
}

// ---- output projection: split-sum in VALU first, then 1x MFMA; fused 1/l
__global__ __launch_bounds__(256) void oproj_kernel(
    const unsigned short* __restrict__ Opart, const float* __restrict__ Lbuf,
    const float* __restrict__ Wo, const float* __restrict__ bo,
    float* __restrict__ out)
{
    const int t = threadIdx.x, w = t >> 6, lane = t & 63;
    const int quad = lane >> 4, l16 = lane & 15;
    const int n0 = blockIdx.x * 16, colbase = w * 64;
    const int qt32 = (n0 >> 7) * 32;
    const int rbase = n0 & 127;

    float linv[4];
#pragma unroll
    for (int hh = 0; hh < 4; ++hh) {
        float ls = 0.f;
#pragma unroll
        for (int sp = 0; sp < NSPLIT; ++sp)
            ls += Lbuf[(qt32 + hh * 8 + sp) * 128 + rbase + l16];
        linv[hh] = 1.f / ls;
    }
    v4f acc[4];
#pragma unroll
    for (int ct = 0; ct < 4; ++ct) {
        const float bb = bo[colbase + ct * 16 + l16];
        acc[ct] = v4f{bb, bb, bb, bb};
    }
#pragma unroll
    for (int k0 = 0; k0 < 256; k0 += 32) {
        const int hh = k0 >> 6;
        const int d0 = (k0 & 63) + quad * 8;
        float av[8] = {0.f, 0.f, 0.f, 0.f, 0.f, 0.f, 0.f, 0.f};
#pragma unroll
        for (int sp = 0; sp < NSPLIT; ++sp) {
            const v8s A = *(const v8s*)(Opart + (size_t)(qt32 + hh * 8 + sp) * 8192
                                        + (rbase + l16) * 64 + d0);
#pragma unroll
            for (int j = 0; j < 8; ++j) av[j] += bf2f((unsigned short)A[j]);
        }
#pragma unroll
        for (int j = 0; j < 8; ++j) av[j] *= linv[hh];
        v8s ah, al;
        split8(av, ah, al);
#pragma unroll
        for (int ct = 0; ct < 4; ++ct) {
            v8s wh, wl;
            wgather(Wo, k0 + quad * 8, colbase + ct * 16 + l16, wh, wl);
            acc[ct] = __builtin_amdgcn_mfma_f32_16x16x32_bf16(al, wh, acc[ct], 0, 0, 0);
            acc[ct] = __builtin_amdgcn_mfma_f32_16x16x32_bf16(ah, wl, acc[ct], 0, 0, 0);
            acc[ct] = __builtin_amdgcn_mfma_f32_16x16x32_bf16(ah, wh, acc[ct], 0, 0, 0);
        }
    }
#pragma unroll
    for (int ct = 0; ct < 4; ++ct)
#pragma unroll
        for (int r = 0; r < 4; ++r)
            out[(size_t)(n0 + quad * 4 + r) * 256 + colbase + ct * 16 + l16] = acc[ct][r];
}

extern "C" void kernel_launch(void* const* d_in, const int* in_sizes, int n_in,
                              void* d_out, int out_size, void* d_ws, size_t ws_size,
                              hipStream_t stream) {
    const float* query = (const float*)d_in[0];
    const float* key   = (const float*)d_in[1];
    const float* value = (const float*)d_in[2];
    const float* Wq    = (const float*)d_in[3];
    const float* bq    = (const float*)d_in[4];
    const float* Wk    = (const float*)d_in[5];
    const float* bk    = (const float*)d_in[6];
    const float* Wv    = (const float*)d_in[7];
    const float* bv    = (const float*)d_in[8];
    const float* Wo    = (const float*)d_in[9];
    const float* bo    = (const float*)d_in[10];
    const int*   nex   = (const int*)d_in[11];

    char* ws = (char*)d_ws;
    unsigned short* Qb    = (unsigned short*)(ws);                              // 2 MB
    unsigned short* Kb    = (unsigned short*)(ws + (size_t)2 * 1024 * 1024);    // 4 MB
    unsigned short* Vt    = (unsigned short*)(ws + (size_t)6 * 1024 * 1024);    // 4 MB
    unsigned short* Opart = (unsigned short*)(ws + (size_t)10 * 1024 * 1024);   // 16 MB bf16
    float* Lbuf           = (float*)(ws + (size_t)26 * 1024 * 1024);            // 512 KB
    float* out            = (float*)d_out;

    qkv_kernel<<<1280, 256, 0, stream>>>(query, key, value, Wq, Wk, Wv,
                                         bq, bk, bv, Qb, Kb, Vt, nex);
    attn_kernel<<<1024, 256, 0, stream>>>(Qb, Kb, Vt, Opart, Lbuf);
    oproj_kernel<<<256, 256, 0, stream>>>(Opart, Lbuf, Wo, bo, out);
}

// Round 12
// 160.295 us; speedup vs baseline: 1.4308x; 1.0202x over previous
//
#include <hip/hip_runtime.h>
#include <hip/hip_bf16.h>

#define NQ 4096
#define NK 8192
#define NSPLIT 8
#define KSPAN (NK / NSPLIT)
#define BK 64

// 0.125 (1/sqrt(64)) * log2(e): scores in log2 domain; no max subtraction needed
// (|S| <= ~14 in log2 domain, exp2 can't overflow; scale cancels in O/l)
#define QSCALE 0.1803368801111204f

typedef short v8s __attribute__((ext_vector_type(8)));
typedef float v4f __attribute__((ext_vector_type(4)));

static __device__ __forceinline__ unsigned short f2bf(float f) {
    unsigned int u = __float_as_uint(f);
    u = (u + 0x7FFFu + ((u >> 16) & 1u)) >> 16;
    return (unsigned short)u;
}
static __device__ __forceinline__ float bf2f(unsigned short h) {
    return __uint_as_float(((unsigned int)h) << 16);
}
static __device__ __forceinline__ unsigned int pkbf(float a, float b) {
    union { __hip_bfloat162 h; unsigned int u; } cv;
    cv.h = __float22bfloat162_rn(make_float2(a, b));
    return cv.u;
}
static __device__ __forceinline__ void split8(const float* a, v8s& hi, v8s& lo) {
#pragma unroll
    for (int j = 0; j < 8; ++j) {
        unsigned short h = f2bf(a[j]);
        hi[j] = (short)h;
        lo[j] = (short)f2bf(a[j] - bf2f(h));
    }
}
// gather a W^T[col][k0..k0+7] B-fragment from fp32 W[k][col] (ld=256), hi/lo planes
static __device__ __forceinline__ void wgather(const float* __restrict__ W,
                                               int k0, int col, v8s& wh, v8s& wl) {
    float wv[8];
#pragma unroll
    for (int j = 0; j < 8; ++j) wv[j] = W[(size_t)(k0 + j) * 256 + col];
    split8(wv, wh, wl);
}
// async global->LDS, 16B/lane; dest = uniform base + lane*16
static __device__ __forceinline__ void dma16(const unsigned short* g, unsigned short* l) {
    __builtin_amdgcn_global_load_lds(
        (const __attribute__((address_space(1))) unsigned int*)(const void*)g,
        (__attribute__((address_space(3))) unsigned int*)(void*)l, 16, 0, 0);
}

// ---- fused QKV projection, inline W split (R9, proven)
__global__ __launch_bounds__(256) void qkv_kernel(
    const float* __restrict__ query, const float* __restrict__ key,
    const float* __restrict__ value,
    const float* __restrict__ Wq, const float* __restrict__ Wk,
    const float* __restrict__ Wv,
    const float* __restrict__ bq, const float* __restrict__ bk,
    const float* __restrict__ bv,
    unsigned short* __restrict__ Qb, unsigned short* __restrict__ Kb,
    unsigned short* __restrict__ Vt, const int* __restrict__ nexp)
{
    const int b = blockIdx.x;
    const int t = threadIdx.x, w = t >> 6, lane = t & 63;
    const int quad = lane >> 4, l16 = lane & 15;
    const int colbase = w * 64;

    if (b < 256) {
        const int n0 = b * 16;
        v4f acc[4];
#pragma unroll
        for (int ct = 0; ct < 4; ++ct) {
            const float bb = bq[colbase + ct * 16 + l16];
            acc[ct] = v4f{bb, bb, bb, bb};
        }
        const float* arow = query + (size_t)(n0 + l16) * 256 + quad * 8;
#pragma unroll
        for (int k0 = 0; k0 < 256; k0 += 32) {
            float av[8];
            *(float4*)av = *(const float4*)(arow + k0);
            *(float4*)(av + 4) = *(const float4*)(arow + k0 + 4);
            v8s ah, al;
            split8(av, ah, al);
#pragma unroll
            for (int ct = 0; ct < 4; ++ct) {
                v8s wh, wl;
                wgather(Wq, k0 + quad * 8, colbase + ct * 16 + l16, wh, wl);
                acc[ct] = __builtin_amdgcn_mfma_f32_16x16x32_bf16(al, wh, acc[ct], 0, 0, 0);
                acc[ct] = __builtin_amdgcn_mfma_f32_16x16x32_bf16(ah, wl, acc[ct], 0, 0, 0);
                acc[ct] = __builtin_amdgcn_mfma_f32_16x16x32_bf16(ah, wh, acc[ct], 0, 0, 0);
            }
        }
#pragma unroll
        for (int ct = 0; ct < 4; ++ct) {
            const int d = ct * 16 + l16;
            const int j = d >> 1;
            const float freq = exp2f(-(float)(j & 15) * 1.66096404744368f);
            const bool isx = (j < 16), odd = (d & 1);
#pragma unroll
            for (int r = 0; r < 4; ++r) {
                const int p = n0 + quad * 4 + r;
                const float tpos = isx ? (float)(p & 63) : (float)(p >> 6);
                float sn, cs;
                __sincosf(tpos * freq, &sn, &cs);
                const float x = acc[ct][r];
                const float xp = __shfl_xor(x, 1, 64);
                const float y = odd ? fmaf(x, cs, xp * sn) : fmaf(x, cs, -xp * sn);
                Qb[((size_t)(w * NQ + p) << 6) + d] = f2bf(y * QSCALE);
            }
        }
    } else {
        const bool isK = (b < 768);
        const int n0 = (isK ? (b - 256) : (b - 768)) * 16;
        const float* X = isK ? key : value;
        const float* W = isK ? Wk : Wv;
        const float* bias = isK ? bk : bv;
        v4f acc[4];
#pragma unroll
        for (int ct = 0; ct < 4; ++ct) {
            const float bb = bias[colbase + ct * 16 + l16];
            acc[ct] = v4f{bb, bb, bb, bb};
        }
        const float* arow = X + (size_t)(n0 + l16) * 64 + quad * 8;
#pragma unroll
        for (int k0 = 0; k0 < 64; k0 += 32) {
            float av[8];
            *(float4*)av = *(const float4*)(arow + k0);
            *(float4*)(av + 4) = *(const float4*)(arow + k0 + 4);
            v8s ah, al;
            split8(av, ah, al);
#pragma unroll
            for (int ct = 0; ct < 4; ++ct) {
                v8s wh, wl;
                wgather(W, k0 + quad * 8, colbase + ct * 16 + l16, wh, wl);
                acc[ct] = __builtin_amdgcn_mfma_f32_16x16x32_bf16(al, wh, acc[ct], 0, 0, 0);
                acc[ct] = __builtin_amdgcn_mfma_f32_16x16x32_bf16(ah, wl, acc[ct], 0, 0, 0);
                acc[ct] = __builtin_amdgcn_mfma_f32_16x16x32_bf16(ah, wh, acc[ct], 0, 0, 0);
            }
        }
        if (isK) {
            const int nro = NK - *nexp;
#pragma unroll
            for (int ct = 0; ct < 4; ++ct) {
                const int d = ct * 16 + l16;
                const int j = d >> 1;
                const float freq = exp2f(-(float)(j & 15) * 1.66096404744368f);
                const bool isx = (j < 16), odd = (d & 1);
#pragma unroll
                for (int r = 0; r < 4; ++r) {
                    const int p = n0 + quad * 4 + r;
                    const int pc = p & 4095;
                    const float tpos = isx ? (float)(pc & 63) : (float)(pc >> 6);
                    float sn, cs;
                    __sincosf(tpos * freq, &sn, &cs);
                    const float x = acc[ct][r];
                    const float xp = __shfl_xor(x, 1, 64);
                    float y = odd ? fmaf(x, cs, xp * sn) : fmaf(x, cs, -xp * sn);
                    y = (p < nro) ? y : x;
                    Kb[((size_t)(w * NK + p) << 6) + d] = f2bf(y);
                }
            }
        } else {
#pragma unroll
            for (int ct = 0; ct < 4; ++ct) {
                const int col = colbase + ct * 16 + l16;
                uint2 u = make_uint2(pkbf(acc[ct][0], acc[ct][1]),
                                     pkbf(acc[ct][2], acc[ct][3]));
                *(uint2*)(Vt + (size_t)col * NK + n0 + quad * 4) = u;
            }
        }
    }
}

// ---- flash attention: 1024 blocks = qt(32) x h(4) x s(8); 4 waves x 32 q-rows
// Single-buffer DMA staging (R9). NO P round-trip: PV's B-operand is the lane's
// own S-registers; the k-permutation sigma(quad,jj)=32t+16(jj>>2)+4q+(jj&3) is
// absorbed into V's LDS read offsets (b64 x4, 2-way-aliased = conflict-free).
__global__ __launch_bounds__(256) void attn_kernel(
    const unsigned short* __restrict__ Qb, const unsigned short* __restrict__ Kb,
    const unsigned short* __restrict__ Vt, unsigned short* __restrict__ Opart,
    float* __restrict__ Lbuf)
{
    __shared__ alignas(16) unsigned short Kl[64 * 64];
    __shared__ alignas(16) unsigned short Vl[64 * 64];

    const int blk = blockIdx.x;
    const int s = blk & 7, h = (blk >> 3) & 3, qt = blk >> 5;
    const int t = threadIdx.x;
    const int w = t >> 6, lane = t & 63;
    const int quad = lane >> 4, l16 = lane & 15;

    const int q0 = qt * 128 + w * 32;
    v8s qf[2][2];
#pragma unroll
    for (int g = 0; g < 2; ++g) {
        const unsigned short* qr = Qb + ((size_t)(h * NQ + q0 + g * 16 + l16) << 6) + quad * 8;
        qf[g][0] = *(const v8s*)qr;
        qf[g][1] = *(const v8s*)(qr + 32);
    }

    v4f O[4][2];
#pragma unroll
    for (int dt = 0; dt < 4; ++dt)
#pragma unroll
        for (int g = 0; g < 2; ++g) O[dt][g] = v4f{0.f, 0.f, 0.f, 0.f};
    float psum[2] = {0.f, 0.f};

    const unsigned short* Kbase = Kb + (((size_t)h * NK + s * KSPAN) << 6);
    const unsigned short* Vbase = Vt + (size_t)(h * 64) * NK + s * KSPAN;

    const int srow = lane >> 3;            // 0..7
    const int schunk = (lane & 7) ^ srow;  // swizzled 16B chunk
    const int c0off = ((quad ^ (l16 & 7)) * 8);
    const int c1off = c0off ^ 32;
    // sigma-permuted V b64 offsets (loop-invariant, swizzle-aware):
    // kloc = 32t + 16h2 + 4*quad + rr  ->  chunk=4t+2h2+(quad>>1), within=4*(quad&1)
    int voff[2][2];
#pragma unroll
    for (int tv = 0; tv < 2; ++tv)
#pragma unroll
        for (int h2 = 0; h2 < 2; ++h2)
            voff[tv][h2] = (((4 * tv + 2 * h2 + (quad >> 1)) ^ (l16 & 7)) << 3) + 4 * (quad & 1);

    for (int k0 = 0; k0 < KSPAN; k0 += BK) {
        __syncthreads();
#pragma unroll
        for (int half = 0; half < 2; ++half) {
            const int r0 = w * 16 + half * 8;
            dma16(Kbase + ((size_t)(k0 + r0 + srow) << 6) + schunk * 8, &Kl[r0 * 64]);
            dma16(Vbase + (size_t)(r0 + srow) * NK + k0 + schunk * 8, &Vl[r0 * 64]);
        }
        __syncthreads();

        // S^T = K Q^T ; exp2 immediately (no max); pack P into B-fragments in-regs
        v8s pf[2][2]; // [g][t]: slots 0-3 <- e[2t][0..3], slots 4-7 <- e[2t+1][0..3]
#pragma unroll
        for (int tt = 0; tt < 4; ++tt) {
            const unsigned short* kr = &Kl[(tt * 16 + l16) * 64];
            const v8s kf0 = *(const v8s*)(kr + c0off);
            const v8s kf1 = *(const v8s*)(kr + c1off);
#pragma unroll
            for (int g = 0; g < 2; ++g) {
                v4f a = v4f{0.f, 0.f, 0.f, 0.f};
                a = __builtin_amdgcn_mfma_f32_16x16x32_bf16(kf0, qf[g][0], a, 0, 0, 0);
                a = __builtin_amdgcn_mfma_f32_16x16x32_bf16(kf1, qf[g][1], a, 0, 0, 0);
                const float e0 = __builtin_amdgcn_exp2f(a[0]);
                const float e1 = __builtin_amdgcn_exp2f(a[1]);
                const float e2 = __builtin_amdgcn_exp2f(a[2]);
                const float e3 = __builtin_amdgcn_exp2f(a[3]);
                psum[g] += (e0 + e1) + (e2 + e3);
                unsigned int* pp = (unsigned int*)&pf[g][tt >> 1];
                pp[(tt & 1) * 2 + 0] = pkbf(e0, e1);
                pp[(tt & 1) * 2 + 1] = pkbf(e2, e3);
            }
        }

        // O^T += V^T P^T with sigma-permuted V fragments (pure register B-operand)
#pragma unroll
        for (int dt = 0; dt < 4; ++dt) {
            const unsigned short* vr = &Vl[(dt * 16 + l16) * 64];
#pragma unroll
            for (int tv = 0; tv < 2; ++tv) {
                union { v8s s; uint2 u[2]; } vv;
                vv.u[0] = *(const uint2*)(vr + voff[tv][0]);
                vv.u[1] = *(const uint2*)(vr + voff[tv][1]);
#pragma unroll
                for (int g = 0; g < 2; ++g)
                    O[dt][g] = __builtin_amdgcn_mfma_f32_16x16x32_bf16(vv.s, pf[g][tv], O[dt][g], 0, 0, 0);
            }
        }
    }

#pragma unroll
    for (int g = 0; g < 2; ++g) {
        float p = psum[g];
        p += __shfl_xor(p, 16, 64);
        p += __shfl_xor(p, 32, 64);
        psum[g] = p;
    }
    unsigned short* Ob = Opart + (size_t)blk * 8192;
#pragma unroll
    for (int g = 0; g < 2; ++g) {
        const int row = w * 32 + g * 16 + l16;
#pragma unroll
        for (int dt = 0; dt < 4; ++dt) {
            uint2 u = make_uint2(pkbf(O[dt][g][0], O[dt][g][1]),
                                 pkbf(O[dt][g][2], O[dt][g][3]));
            *(uint2*)(Ob + row * 64 + dt * 16 + quad * 4) = u;
        }
        if (quad == 0) Lbuf[blk * 128 + row] = psum[g];
    }
}

// ---- output projection: split-sum in VALU first, then 1x MFMA; fused 1/l
__global__ __launch_bounds__(256) void oproj_kernel(
    const unsigned short* __restrict__ Opart, const float* __restrict__ Lbuf,
    const float* __restrict__ Wo, const float* __restrict__ bo,
    float* __restrict__ out)
{
    const int t = threadIdx.x, w = t >> 6, lane = t & 63;
    const int quad = lane >> 4, l16 = lane & 15;
    const int n0 = blockIdx.x * 16, colbase = w * 64;
    const int qt32 = (n0 >> 7) * 32;
    const int rbase = n0 & 127;

    float linv[4];
#pragma unroll
    for (int hh = 0; hh < 4; ++hh) {
        float ls = 0.f;
#pragma unroll
        for (int sp = 0; sp < NSPLIT; ++sp)
            ls += Lbuf[(qt32 + hh * 8 + sp) * 128 + rbase + l16];
        linv[hh] = 1.f / ls;
    }
    v4f acc[4];
#pragma unroll
    for (int ct = 0; ct < 4; ++ct) {
        const float bb = bo[colbase + ct * 16 + l16];
        acc[ct] = v4f{bb, bb, bb, bb};
    }
#pragma unroll
    for (int k0 = 0; k0 < 256; k0 += 32) {
        const int hh = k0 >> 6;
        const int d0 = (k0 & 63) + quad * 8;
        float av[8] = {0.f, 0.f, 0.f, 0.f, 0.f, 0.f, 0.f, 0.f};
#pragma unroll
        for (int sp = 0; sp < NSPLIT; ++sp) {
            const v8s A = *(const v8s*)(Opart + (size_t)(qt32 + hh * 8 + sp) * 8192
                                        + (rbase + l16) * 64 + d0);
#pragma unroll
            for (int j = 0; j < 8; ++j) av[j] += bf2f((unsigned short)A[j]);
        }
#pragma unroll
        for (int j = 0; j < 8; ++j) av[j] *= linv[hh];
        v8s ah, al;
        split8(av, ah, al);
#pragma unroll
        for (int ct = 0; ct < 4; ++ct) {
            v8s wh, wl;
            wgather(Wo, k0 + quad * 8, colbase + ct * 16 + l16, wh, wl);
            acc[ct] = __builtin_amdgcn_mfma_f32_16x16x32_bf16(al, wh, acc[ct], 0, 0, 0);
            acc[ct] = __builtin_amdgcn_mfma_f32_16x16x32_bf16(ah, wl, acc[ct], 0, 0, 0);
            acc[ct] = __builtin_amdgcn_mfma_f32_16x16x32_bf16(ah, wh, acc[ct], 0, 0, 0);
        }
    }
#pragma unroll
    for (int ct = 0; ct < 4; ++ct)
#pragma unroll
        for (int r = 0; r < 4; ++r)
            out[(size_t)(n0 + quad * 4 + r) * 256 + colbase + ct * 16 + l16] = acc[ct][r];
}

extern "C" void kernel_launch(void* const* d_in, const int* in_sizes, int n_in,
                              void* d_out, int out_size, void* d_ws, size_t ws_size,
                              hipStream_t stream) {
    const float* query = (const float*)d_in[0];
    const float* key   = (const float*)d_in[1];
    const float* value = (const float*)d_in[2];
    const float* Wq    = (const float*)d_in[3];
    const float* bq    = (const float*)d_in[4];
    const float* Wk    = (const float*)d_in[5];
    const float* bk    = (const float*)d_in[6];
    const float* Wv    = (const float*)d_in[7];
    const float* bv    = (const float*)d_in[8];
    const float* Wo    = (const float*)d_in[9];
    const float* bo    = (const float*)d_in[10];
    const int*   nex   = (const int*)d_in[11];

    char* ws = (char*)d_ws;
    unsigned short* Qb    = (unsigned short*)(ws);                              // 2 MB
    unsigned short* Kb    = (unsigned short*)(ws + (size_t)2 * 1024 * 1024);    // 4 MB
    unsigned short* Vt    = (unsigned short*)(ws + (size_t)6 * 1024 * 1024);    // 4 MB
    unsigned short* Opart = (unsigned short*)(ws + (size_t)10 * 1024 * 1024);   // 16 MB bf16
    float* Lbuf           = (float*)(ws + (size_t)26 * 1024 * 1024);            // 512 KB
    float* out            = (float*)d_out;

    qkv_kernel<<<1280, 256, 0, stream>>>(query, key, value, Wq, Wk, Wv,
                                         bq, bk, bv, Qb, Kb, Vt, nex);
    attn_kernel<<<1024, 256, 0, stream>>>(Qb, Kb, Vt, Opart, Lbuf);
    oproj_kernel<<<256, 256, 0, stream>>>(Opart, Lbuf, Wo, bo, out);
}